// Round 3
// baseline (651.493 us; speedup 1.0000x reference)
//
#include <hip/hip_runtime.h>

// RiemannianLoRAEmbedding: out[b,s,:] = clamp(mobius_add(clamp(W[idx]), clamp(0.1 * B[idx] @ A)))
// Shapes: indices [8,4096] i32, W [128000,1024] f32, A [16,1024] f32, B [128000,16] f32.
// Memory-bound gather: one block = 16 tokens, 256 threads, each thread owns 4 contiguous d's.
// A-fragment cached in registers (16 x float4) and reused across the block's 16 tokens so
// lora_A L2 traffic is 64KB/block (128 MB total) instead of 64KB/token (2 GB).

constexpr int D           = 1024;
constexpr int R           = 16;
constexpr int TOK_PER_BLK = 16;
constexpr int THREADS     = 256;   // D/4 lanes of float4
constexpr float EPSV      = 1e-5f;
constexpr float MAXNORM   = 1.0f - 1e-5f;
constexpr float SCALING   = 0.1f;

__global__ __launch_bounds__(THREADS) void rlora_embed_kernel(
    const int*   __restrict__ indices,
    const float* __restrict__ base_weight,
    const float* __restrict__ lora_A,
    const float* __restrict__ lora_B,
    float*       __restrict__ out,
    int n_tok)
{
    __shared__ int   s_idx[TOK_PER_BLK];
    __shared__ float s_b[TOK_PER_BLK][R];
    __shared__ float s_red[4][3];   // per-wave partials: x2, y2, xy
    __shared__ float s_red2[4];     // per-wave partials: |res|^2

    const int tid  = threadIdx.x;
    const int lane = tid & 63;
    const int wave = tid >> 6;
    const int tok0 = blockIdx.x * TOK_PER_BLK;
    const int d0   = tid * 4;

    // stage indices for this block's tokens
    if (tid < TOK_PER_BLK) {
        int tok = tok0 + tid;
        s_idx[tid] = indices[tok < n_tok ? tok : (n_tok - 1)];
    }
    __syncthreads();

    // stage lora_B rows: 256 threads = 16 tokens x 16 ranks, coalesced per row
    {
        int t = tid >> 4;
        int r = tid & 15;
        s_b[t][r] = lora_B[(size_t)s_idx[t] * R + r];
    }

    // cache this thread's lora_A fragment in registers: a[r] = A[r][d0..d0+3]
    float4 a[R];
#pragma unroll
    for (int r = 0; r < R; ++r)
        a[r] = *reinterpret_cast<const float4*>(&lora_A[r * D + d0]);

    __syncthreads();

    for (int t = 0; t < TOK_PER_BLK; ++t) {
        const int    tok = tok0 + t;
        const size_t row = (size_t)s_idx[t];

        float4 xv = *reinterpret_cast<const float4*>(&base_weight[row * D + d0]);

        // delta = SCALING * (b_sel @ A), fragment of 4 d's
        float4 dv = make_float4(0.f, 0.f, 0.f, 0.f);
#pragma unroll
        for (int r = 0; r < R; ++r) {
            const float br = s_b[t][r];
            dv.x = fmaf(br, a[r].x, dv.x);
            dv.y = fmaf(br, a[r].y, dv.y);
            dv.z = fmaf(br, a[r].z, dv.z);
            dv.w = fmaf(br, a[r].w, dv.w);
        }
        dv.x *= SCALING; dv.y *= SCALING; dv.z *= SCALING; dv.w *= SCALING;

        // one fused reduction for x.x, d.d, x.d (clamp is a uniform scale, applied analytically)
        float px  = xv.x*xv.x + xv.y*xv.y + xv.z*xv.z + xv.w*xv.w;
        float py  = dv.x*dv.x + dv.y*dv.y + dv.z*dv.z + dv.w*dv.w;
        float pxy = xv.x*dv.x + xv.y*dv.y + xv.z*dv.z + xv.w*dv.w;
#pragma unroll
        for (int off = 32; off > 0; off >>= 1) {
            px  += __shfl_xor(px,  off);
            py  += __shfl_xor(py,  off);
            pxy += __shfl_xor(pxy, off);
        }
        if (lane == 0) { s_red[wave][0] = px; s_red[wave][1] = py; s_red[wave][2] = pxy; }
        __syncthreads();
        float x2 = s_red[0][0] + s_red[1][0] + s_red[2][0] + s_red[3][0];
        float y2 = s_red[0][1] + s_red[1][1] + s_red[2][1] + s_red[3][1];
        float xy = s_red[0][2] + s_red[1][2] + s_red[2][2] + s_red[3][2];

        // clamp_to_ball scales (per-row uniform)
        const float nx = sqrtf(x2);
        const float sx = (nx > MAXNORM) ? (MAXNORM / fmaxf(nx, EPSV)) : 1.0f;
        const float ny = sqrtf(y2);
        const float sy = (ny > MAXNORM) ? (MAXNORM / fmaxf(ny, EPSV)) : 1.0f;
        x2 *= sx * sx;  y2 *= sy * sy;  xy *= sx * sy;
        xv.x *= sx; xv.y *= sx; xv.z *= sx; xv.w *= sx;
        dv.x *= sy; dv.y *= sy; dv.z *= sy; dv.w *= sy;

        // Mobius addition
        const float cx      = 1.0f + 2.0f*xy + y2;   // coefficient on x
        const float cy      = 1.0f - x2;             // coefficient on delta
        const float den     = 1.0f + 2.0f*xy + x2*y2;
        const float inv_den = 1.0f / fmaxf(den, 1e-15f);

        float4 rv;
        rv.x = (cx*xv.x + cy*dv.x) * inv_den;
        rv.y = (cx*xv.y + cy*dv.y) * inv_den;
        rv.z = (cx*xv.z + cy*dv.z) * inv_den;
        rv.w = (cx*xv.w + cy*dv.w) * inv_den;

        // final clamp needs ||res||
        float pr = rv.x*rv.x + rv.y*rv.y + rv.z*rv.z + rv.w*rv.w;
#pragma unroll
        for (int off = 32; off > 0; off >>= 1) pr += __shfl_xor(pr, off);
        if (lane == 0) s_red2[wave] = pr;
        __syncthreads();
        const float r2 = s_red2[0] + s_red2[1] + s_red2[2] + s_red2[3];
        const float nr = sqrtf(r2);
        const float sr = (nr > MAXNORM) ? (MAXNORM / fmaxf(nr, EPSV)) : 1.0f;
        rv.x *= sr; rv.y *= sr; rv.z *= sr; rv.w *= sr;

        if (tok < n_tok)
            *reinterpret_cast<float4*>(&out[(size_t)tok * D + d0]) = rv;
    }
}

extern "C" void kernel_launch(void* const* d_in, const int* in_sizes, int n_in,
                              void* d_out, int out_size, void* d_ws, size_t ws_size,
                              hipStream_t stream)
{
    const int*   indices     = (const int*)d_in[0];
    const float* base_weight = (const float*)d_in[1];
    const float* lora_A      = (const float*)d_in[2];
    const float* lora_B      = (const float*)d_in[3];
    float*       out         = (float*)d_out;

    const int n_tok = in_sizes[0];                       // 8 * 4096 = 32768
    const int grid  = (n_tok + TOK_PER_BLK - 1) / TOK_PER_BLK;

    rlora_embed_kernel<<<grid, THREADS, 0, stream>>>(
        indices, base_weight, lora_A, lora_B, out, n_tok);
}